// Round 4
// baseline (218.034 us; speedup 1.0000x reference)
//
#include <hip/hip_runtime.h>
#include <stdint.h>

// Problem constants
constexpr int B = 32, C = 32, T = 2048, D = 512;
constexpr float ALPHA = 0.1f;
constexpr float BETA  = 0.9f;
constexpr float LOG2_BETA = -0.15200309344504997f;  // log2(0.9)
constexpr float BETA16    = 0.18530201888518410f;   // 0.9^16 (chunk carry factor)

typedef float floatx4 __attribute__((ext_vector_type(4)));
typedef float f32x16  __attribute__((ext_vector_type(16)));

// Tiling: CHUNK=128, 8 sub-threads/channel x SUB=16; cooperative halo
// (one 16-chunk per side per sub-thread, composed via beta^16 Horner).
// PAD=389 (odd, 5 mod 32): phase-B column reads land 64 lanes on 32 banks
// 2-way = free (PAD=390 was 4-way: lane stride 6 banks, gcd(6,32)=2).
constexpr int CHUNK = 128;
constexpr int SUB   = 16;
constexpr int NSUB  = CHUNK / SUB;          // 8
constexpr int LEAD  = 132;                  // 128 halo + 1 diff + 3 align
constexpr int WIN   = LEAD + CHUNK + 128;   // 388
constexpr int PAD   = WIN + 1;              // 389

// ---------------------------------------------------------------------------
// Kernel 1: W_comb[e,c] = sum_d W_lin[e,d]*W_ve[d,c];
//           b_comb[e]   = sum_d W_lin[e,d]*b_ve[d] + b_lin[e]
// ---------------------------------------------------------------------------
__global__ __launch_bounds__(256) void combine_weights(
    const float* __restrict__ W_ve, const float* __restrict__ b_ve,
    const float* __restrict__ W_lin, const float* __restrict__ b_lin,
    float* __restrict__ W_comb, float* __restrict__ b_comb) {
  int e  = blockIdx.x;
  int c  = threadIdx.x & 31;
  int ds = threadIdx.x >> 5;
  float acc = 0.f, accb = 0.f;
#pragma unroll 4
  for (int i = 0; i < 64; ++i) {
    int d = ds * 64 + i;
    float wl = W_lin[e * D + d];
    acc  += wl * W_ve[d * C + c];
    accb += wl * b_ve[d];
  }
  __shared__ float red[8][33];
  __shared__ float redb[8];
  red[ds][c] = acc;
  if (c == 0) redb[ds] = accb;
  __syncthreads();
  if (ds == 0) {
    float ssum = 0.f;
#pragma unroll
    for (int k = 0; k < 8; ++k) ssum += red[k][c];
    W_comb[e * C + c] = ssum;
    if (c == 0) {
      float sb = 0.f;
#pragma unroll
      for (int k = 0; k < 8; ++k) sb += redb[k];
      b_comb[e] = sb + b_lin[e];
    }
  }
}

// SMEM row loads: one s-tile row (32 floats) into 32 SGPRs.
// Address MUST be a proven-uniform SGPR pair (readfirstlane-hoisted by the
// caller -- hipcc's divergence analysis can't prove threadIdx-derived
// uniformity, round-3 compile error). Early-clobber dest tuples.
#define SLOAD2(d0, d1, addr)                              \
  asm volatile("s_load_dwordx16 %0, %2, 0x0\n\t"          \
               "s_load_dwordx16 %1, %2, 0x40"             \
               : "=&s"(d0), "=&s"(d1) : "s"(addr))
// Rule #18: hipcc hoists register-only VALU past inline-asm waits;
// sched_barrier(0) right after the waitcnt is the required fence.
#define SWAIT()                                           \
  do {                                                    \
    asm volatile("s_waitcnt lgkmcnt(0)");                 \
    __builtin_amdgcn_sched_barrier(0);                    \
  } while (0)

// ---------------------------------------------------------------------------
// Kernel 2 (fused): diff + bidirectional EWMA in channel space + K=32 GEMM.
// grid = (T/CHUNK=16, B=32) = 512 blocks, 256 threads.
// Phase C reads the s-tile via s_load into SGPRs (wave-uniform operand
// broadcasts for free in the VALU datapath) -> zero LDS traffic in the GEMM.
// s-tile round-trips through the workspace (16 KB/block, L2-resident).
// ---------------------------------------------------------------------------
__global__ __launch_bounds__(256) void fused_main(
    const float* __restrict__ x, const float* __restrict__ W_comb,
    const float* __restrict__ b_comb, float* __restrict__ s_ws,
    float* __restrict__ out) {
  int b   = blockIdx.y;
  int t0  = blockIdx.x * CHUNK;
  int wlo = t0 - LEAD;  // staged window covers global t in [wlo, wlo+WIN)

  __shared__ float xl[C * PAD];     // 48.6 KB
  __shared__ float Lf[2][NSUB][C];  // fwd chunk sums: [0]=halo [1]=main
  __shared__ float Lb[2][NSUB][C];  // bwd chunk sums
  const float* xb = x + (size_t)b * C * T;
  float* sblk = s_ws + ((size_t)b * (T / CHUNK) + blockIdx.x) * (CHUNK * C);

  int c   = threadIdx.x & 31;
  int sub = threadIdx.x >> 5;

  // last-diff for the exact bwd init-term correction
  float dlast = xb[c * T + (T - 1)] - xb[c * T + (T - 2)];

  // ---- Phase A: staging ----
  if (wlo >= 0 && wlo + WIN <= T) {
    // interior (bx 2..14): 16B-aligned float4 global loads (wlo%4==0).
    for (int idx = threadIdx.x; idx < C * (WIN / 4); idx += 256) {
      int cc = idx / (WIN / 4);  // compile-time divisor (97)
      int q  = idx - cc * (WIN / 4);
      float4 v   = *(const float4*)(xb + cc * T + wlo + 4 * q);
      float* dst = xl + cc * PAD + 4 * q;
      dst[0] = v.x; dst[1] = v.y; dst[2] = v.z; dst[3] = v.w;
    }
  } else {
    // edge (bx 0,1,15): scalar clamped staging (DD==0 for t<=0, t>=T).
    for (int idx = threadIdx.x; idx < C * WIN; idx += 256) {
      int cc = idx / WIN;  // compile-time divisor (388)
      int tt = idx - cc * WIN;
      int t  = min(max(wlo + tt, 0), T - 1);
      xl[cc * PAD + tt] = xb[cc * T + t];
    }
  }

  // W rows + bias into registers (overlaps staging latency)
  int li   = threadIdx.x & 127;
  int half = threadIdx.x >> 7;
  int e0   = li * 4;
  float w[4][C], bias[4];
#pragma unroll
  for (int j = 0; j < 4; ++j) {
    const float4* wr = (const float4*)(W_comb + (e0 + j) * C);
#pragma unroll
    for (int c4 = 0; c4 < C / 4; ++c4) {
      float4 wv = wr[c4];
      w[j][c4 * 4 + 0] = wv.x;
      w[j][c4 * 4 + 1] = wv.y;
      w[j][c4 * 4 + 2] = wv.z;
      w[j][c4 * 4 + 3] = wv.w;
    }
    bias[j] = b_comb[e0 + j];
  }
  __syncthreads();

  // ---- Phase B1: per-16-chunk local scans (zero-init) ----
  int ts = t0 + sub * SUB;
  const float* xc = xl + c * PAD - wlo;
#define DD(t) (xc[(t)] - xc[(t) - 1])

  int ha = t0 - 128   + sub * SUB;  // fwd-halo chunk
  int ba = t0 + CHUNK + sub * SUB;  // bwd-halo chunk
  float fh = 0.f, bh = 0.f;
#pragma unroll
  for (int i = 0; i < SUB; ++i) {
    fh = ALPHA * DD(ha + i)           + BETA * fh;
    bh = ALPHA * DD(ba + SUB - 1 - i) + BETA * bh;
  }
  float lr[SUB], rl[SUB];
  float fm = 0.f, bm = 0.f;
#pragma unroll
  for (int i = 0; i < SUB; ++i) {
    fm = ALPHA * DD(ts + i) + BETA * fm;
    lr[i] = fm;
    bm = ALPHA * DD(ts + SUB - 1 - i) + BETA * bm;
    rl[SUB - 1 - i] = bm;
  }
  Lf[0][sub][c] = fh;
  Lf[1][sub][c] = lr[SUB - 1];
  Lb[0][sub][c] = bh;
  Lb[1][sub][c] = rl[0];
  __syncthreads();
#undef DD

  // ---- Phase B2: Horner carry composition + combine ----
  float Cc = 0.f, Bc = 0.f;
#pragma unroll
  for (int h = 0; h < NSUB; ++h) {
    Cc = BETA16 * Cc + Lf[0][h][c];
    Bc = BETA16 * Bc + Lb[0][NSUB - 1 - h][c];
  }
#pragma unroll
  for (int j = 0; j < NSUB - 1; ++j) {  // predicated trip
    float cn = BETA16 * Cc + Lf[1][j][c];
    float bn = BETA16 * Bc + Lb[1][NSUB - 1 - j][c];
    Cc = (j < sub)            ? cn : Cc;
    Bc = (NSUB - 1 - j > sub) ? bn : Bc;
  }
  float f = BETA * Cc;
#pragma unroll
  for (int i = 0; i < SUB; ++i) { lr[i] += f; f *= BETA; }
  float g = BETA * Bc;
  float e = exp2f((float)(T - ts - (SUB - 1)) * LOG2_BETA);  // beta^(T-te)
#pragma unroll
  for (int i = SUB - 1; i >= 0; --i) {
    lr[i] = 0.5f * (lr[i] + (rl[i] + g) + e * dlast);
    g *= BETA;
    e *= BETA;
  }

  // ---- store s-tile to workspace (regular stores: must land in L2) ----
  {
    float* srw = sblk + (sub * SUB) * C + c;
#pragma unroll
    for (int i = 0; i < SUB; ++i) srw[i * C] = lr[i];
  }
  __syncthreads();  // drains vmcnt(0) -> s-tile visible to SMEM reads

  // ---- Phase C: GEMM with SGPR-resident s rows ----
  const float* srow = sblk + half * (CHUNK / 2) * C;
  // readfirstlane-hoist the (wave-uniform) base into SGPRs so the "s"
  // constraint on SLOAD2 is satisfiable (HK pattern).
  uint64_t srp_raw = (uint64_t)(uintptr_t)srow;
  uint32_t srp_lo = __builtin_amdgcn_readfirstlane((uint32_t)srp_raw);
  uint32_t srp_hi = __builtin_amdgcn_readfirstlane((uint32_t)(srp_raw >> 32));
  uint64_t srp = ((uint64_t)srp_hi << 32) | srp_lo;
  float* orow = out + ((size_t)b * T + t0 + half * (CHUNK / 2)) * D + e0;

  // one t-row: 128 fmac, each v_fmac_f32 v_acc, s_sval, v_w (1 SGPR legal).
  // Summation order identical to previous kernel: even c -> a, odd c -> a2,
  // ascending c (absmax bit-stable).
  auto gemm_row = [&](int t, const f32x16& s0, const f32x16& s1) {
    float a[4], a2[4];
#pragma unroll
    for (int j = 0; j < 4; ++j) { a[j] = bias[j]; a2[j] = 0.f; }
#pragma unroll
    for (int k = 0; k < 16; ++k) {
      float sv = s0[k];
      if ((k & 1) == 0) {
#pragma unroll
        for (int j = 0; j < 4; ++j) a[j] += sv * w[j][k];
      } else {
#pragma unroll
        for (int j = 0; j < 4; ++j) a2[j] += sv * w[j][k];
      }
    }
#pragma unroll
    for (int k = 0; k < 16; ++k) {
      float sv = s1[k];
      if ((k & 1) == 0) {
#pragma unroll
        for (int j = 0; j < 4; ++j) a[j] += sv * w[j][16 + k];
      } else {
#pragma unroll
        for (int j = 0; j < 4; ++j) a2[j] += sv * w[j][16 + k];
      }
    }
    floatx4 o;
    o.x = a[0] + a2[0];
    o.y = a[1] + a2[1];
    o.z = a[2] + a2[2];
    o.w = a[3] + a2[3];
    __builtin_nontemporal_store(o, (floatx4*)(orow + (size_t)t * D));
  };

  f32x16 sA0, sA1, sB0, sB1;
  SLOAD2(sA0, sA1, srp);
#pragma unroll 1
  for (int t = 0; t < CHUNK / 2; t += 2) {
    SWAIT();                                              // sA ready
    SLOAD2(sB0, sB1, srp + (uint64_t)(t + 1) * (C * 4));  // prefetch t+1
    gemm_row(t, sA0, sA1);
    SWAIT();                                              // sB ready
    SLOAD2(sA0, sA1, srp + (uint64_t)(t + 2) * (C * 4));  // prefetch t+2
    gemm_row(t + 1, sB0, sB1);
    // t=62 prefetches one row past the half/block region: lands in the
    // (poisoned, never-used) next ws region -- in-bounds, data discarded.
  }
}

// ---------------------------------------------------------------------------
extern "C" void kernel_launch(void* const* d_in, const int* in_sizes, int n_in,
                              void* d_out, int out_size, void* d_ws, size_t ws_size,
                              hipStream_t stream) {
  const float* x     = (const float*)d_in[0];  // [B,C,T]
  const float* W_ve  = (const float*)d_in[1];  // [D,C]
  const float* b_ve  = (const float*)d_in[2];  // [D]
  const float* W_lin = (const float*)d_in[3];  // [D,D]
  const float* b_lin = (const float*)d_in[4];  // [D]
  float* out = (float*)d_out;                  // [B,T,D]

  // workspace: W_comb [D*C] | b_comb [D] | s_ws [512 blocks * 16 KB = 8 MiB]
  float* W_comb = (float*)d_ws;
  float* b_comb = W_comb + (size_t)D * C;
  float* s_ws   = b_comb + D;

  combine_weights<<<D, 256, 0, stream>>>(W_ve, b_ve, W_lin, b_lin, W_comb, b_comb);
  fused_main<<<dim3(T / CHUNK, B), 256, 0, stream>>>(x, W_comb, b_comb, s_ws, out);
}

// Round 5
// 179.906 us; speedup vs baseline: 1.2119x; 1.2119x over previous
//
#include <hip/hip_runtime.h>

// Problem constants
constexpr int B = 32, C = 32, T = 2048, D = 512;
constexpr float ALPHA = 0.1f;
constexpr float BETA  = 0.9f;
constexpr float LOG2_BETA = -0.15200309344504997f;  // log2(0.9)
constexpr float BETA16    = 0.18530201888518410f;   // 0.9^16 (main-chunk carry)
constexpr float BETA14    = 0.22876792454961000f;   // 0.9^14 (halo-chunk carry)

// Native 4-float vector for __builtin_nontemporal_store.
typedef float floatx4 __attribute__((ext_vector_type(4)));

// Tiling: CHUNK=128, 8 sub-threads/channel x SUB=16 main rows each.
// Cooperative halo: HALO=112 per side, one 14-chunk per sub-thread per side
// (beta^112 ~ 7.5e-6 truncation, ~4e-6 absolute -- far below tolerance).
// Chunk sums composed via Horner: BETA14 across halo chunks, BETA16 across
// main chunks. HALO=112 (vs 128) shrinks the staged window so
// LDS = 32*357*4 + 4K = 49.8 KB < 53.3 KB -> 3 blocks/CU resident: one
// block's store-bound GEMM overlaps two others' staging+EWMA.
// PAD=357 (odd, 5 mod 32): phase-B column reads (lane stride PAD floats)
// hit 32 banks 2-way = free (m136).
constexpr int CHUNK = 128;
constexpr int SUB   = 16;                   // main rows per thread
constexpr int SUBH  = 14;                   // halo rows per thread
constexpr int NSUB  = CHUNK / SUB;          // 8
constexpr int HALO  = NSUB * SUBH;          // 112
constexpr int LEAD  = 116;                  // 112 halo + 1 diff + 3 align (mult of 4)
constexpr int WIN   = LEAD + CHUNK + HALO;  // 356
constexpr int PAD   = WIN + 1;              // 357

// ---------------------------------------------------------------------------
// Kernel 1: W_comb[e,c] = sum_d W_lin[e,d]*W_ve[d,c];
//           b_comb[e]   = sum_d W_lin[e,d]*b_ve[d] + b_lin[e]
// (out = smooth_C(diff) @ W_comb^T + b_comb -- EWMA commutes with Linear)
// ---------------------------------------------------------------------------
__global__ __launch_bounds__(256) void combine_weights(
    const float* __restrict__ W_ve, const float* __restrict__ b_ve,
    const float* __restrict__ W_lin, const float* __restrict__ b_lin,
    float* __restrict__ W_comb, float* __restrict__ b_comb) {
  int e  = blockIdx.x;
  int c  = threadIdx.x & 31;
  int ds = threadIdx.x >> 5;
  float acc = 0.f, accb = 0.f;
#pragma unroll 4
  for (int i = 0; i < 64; ++i) {
    int d = ds * 64 + i;
    float wl = W_lin[e * D + d];
    acc  += wl * W_ve[d * C + c];
    accb += wl * b_ve[d];
  }
  __shared__ float red[8][33];
  __shared__ float redb[8];
  red[ds][c] = acc;
  if (c == 0) redb[ds] = accb;
  __syncthreads();
  if (ds == 0) {
    float ssum = 0.f;
#pragma unroll
    for (int k = 0; k < 8; ++k) ssum += red[k][c];
    W_comb[e * C + c] = ssum;
    if (c == 0) {
      float sb = 0.f;
#pragma unroll
      for (int k = 0; k < 8; ++k) sb += redb[k];
      b_comb[e] = sb + b_lin[e];
    }
  }
}

// ---------------------------------------------------------------------------
// Kernel 2 (fused): diff + bidirectional EWMA in channel space + K=32 GEMM.
// grid = (T/CHUNK=16, B=32) = 512 blocks, 256 threads.
// __launch_bounds__(256,3): 3 waves/EU so the register allocator fits
// 3 blocks/CU (<=170 VGPR) -- the w[4][32] load is deferred to phase C
// to keep phase-B peak pressure low.
// ---------------------------------------------------------------------------
__global__ __launch_bounds__(256, 3) void fused_main(
    const float* __restrict__ x, const float* __restrict__ W_comb,
    const float* __restrict__ b_comb, float* __restrict__ out) {
  int b   = blockIdx.y;
  int t0  = blockIdx.x * CHUNK;
  int wlo = t0 - LEAD;  // staged window covers global t in [wlo, wlo+WIN)

  __shared__ float xl[C * PAD];     // 45.7 KB; reused as s-tile in phase C
  __shared__ float Lf[2][NSUB][C];  // fwd chunk sums: [0]=halo [1]=main (2 KB)
  __shared__ float Lb[2][NSUB][C];  // bwd chunk sums (2 KB)
  const float* xb = x + (size_t)b * C * T;

  int c   = threadIdx.x & 31;
  int sub = threadIdx.x >> 5;

  // last-diff for the exact bwd init-term correction
  float dlast = xb[c * T + (T - 1)] - xb[c * T + (T - 2)];

  // ---- Phase A: staging ----
  if (wlo >= 0 && wlo + WIN <= T) {
    // interior (bx 1..14): 16B-aligned float4 global loads (wlo%4==0).
    for (int idx = threadIdx.x; idx < C * (WIN / 4); idx += 256) {
      int cc = idx / (WIN / 4);  // compile-time divisor (89)
      int q  = idx - cc * (WIN / 4);
      float4 v   = *(const float4*)(xb + cc * T + wlo + 4 * q);
      float* dst = xl + cc * PAD + 4 * q;
      dst[0] = v.x; dst[1] = v.y; dst[2] = v.z; dst[3] = v.w;
    }
  } else {
    // edge (bx 0, 15): scalar clamped staging (DD==0 for t<=0, t>=T).
    for (int idx = threadIdx.x; idx < C * WIN; idx += 256) {
      int cc = idx / WIN;  // compile-time divisor (356)
      int tt = idx - cc * WIN;
      int t  = min(max(wlo + tt, 0), T - 1);
      xl[cc * PAD + tt] = xb[cc * T + t];
    }
  }
  __syncthreads();

  // ---- Phase B1: per-chunk local scans (zero-init): fwd+bwd, halo+main ----
  int ts = t0 + sub * SUB;
  const float* xc = xl + c * PAD - wlo;  // index directly by global t
#define DD(t) (xc[(t)] - xc[(t) - 1])

  int ha = t0 - HALO  + sub * SUBH;  // fwd-halo chunk (14 rows)
  int ba = t0 + CHUNK + sub * SUBH;  // bwd-halo chunk (14 rows)
  float fh = 0.f, bh = 0.f;
#pragma unroll
  for (int i = 0; i < SUBH; ++i) {
    fh = ALPHA * DD(ha + i)            + BETA * fh;  // ascending
    bh = ALPHA * DD(ba + SUBH - 1 - i) + BETA * bh;  // descending
  }
  float lr[SUB], rl[SUB];
  float fm = 0.f, bm = 0.f;
#pragma unroll
  for (int i = 0; i < SUB; ++i) {
    fm = ALPHA * DD(ts + i) + BETA * fm;
    lr[i] = fm;  // raw fwd scan (no carry yet)
    bm = ALPHA * DD(ts + SUB - 1 - i) + BETA * bm;
    rl[SUB - 1 - i] = bm;  // raw bwd scan
  }
  Lf[0][sub][c] = fh;
  Lf[1][sub][c] = lr[SUB - 1];
  Lb[0][sub][c] = bh;
  Lb[1][sub][c] = rl[0];
  __syncthreads();  // scratch visible; also: all xl reads done -> xl reusable
#undef DD

  // ---- Phase B2: Horner carry composition + in-register combine ----
  // S(t0-1) = sum_h beta^(14(7-h)) Lf_halo[h]  (BETA14 Horner);
  // main-chunk carry: C_s = beta^(16s) S + sum_{j<s} beta^(16(s-1-j)) Lf_main[j]
  // (BETA16 Horner, predicated trip). B_s mirrored from the right.
  float Cc = 0.f, Bc = 0.f;
#pragma unroll
  for (int h = 0; h < NSUB; ++h) {
    Cc = BETA14 * Cc + Lf[0][h][c];
    Bc = BETA14 * Bc + Lb[0][NSUB - 1 - h][c];
  }
#pragma unroll
  for (int j = 0; j < NSUB - 1; ++j) {  // predicated (sub-dependent trip)
    float cn = BETA16 * Cc + Lf[1][j][c];
    float bn = BETA16 * Bc + Lb[1][NSUB - 1 - j][c];
    Cc = (j < sub)            ? cn : Cc;
    Bc = (NSUB - 1 - j > sub) ? bn : Bc;
  }
  // lr_true[i] = lr_raw[i] + beta^(i+1) C_s ; rl_true[i] = rl_raw[i] + beta^(16-i) B_s
  // plus exact right-edge init term beta^(T-t) * d[T-1]  (since 1-ALPHA == BETA)
  float f = BETA * Cc;
#pragma unroll
  for (int i = 0; i < SUB; ++i) { lr[i] += f; f *= BETA; }
  float g = BETA * Bc;
  float e = exp2f((float)(T - ts - (SUB - 1)) * LOG2_BETA);  // beta^(T-te)
#pragma unroll
  for (int i = SUB - 1; i >= 0; --i) {
    lr[i] = 0.5f * (lr[i] + (rl[i] + g) + e * dlast);
    g *= BETA;
    e *= BETA;
  }

  // ---- s-tile into reused LDS ----
  float* sbuf = xl;  // s[tloc*C + c], tloc in [0, CHUNK)
  {
    int tbase = sub * SUB;
#pragma unroll
    for (int i = 0; i < SUB; ++i) sbuf[(tbase + i) * C + c] = lr[i];
  }

  // W rows + bias into registers, loaded HERE (after lr/rl pressure is dead;
  // global loads issue before the barrier, latency hides under the wait).
  int li   = threadIdx.x & 127;
  int half = threadIdx.x >> 7;
  int e0   = li * 4;
  float w[4][C], bias[4];
#pragma unroll
  for (int j = 0; j < 4; ++j) {
    const float4* wr = (const float4*)(W_comb + (e0 + j) * C);
#pragma unroll
    for (int c4 = 0; c4 < C / 4; ++c4) {
      float4 wv = wr[c4];
      w[j][c4 * 4 + 0] = wv.x;
      w[j][c4 * 4 + 1] = wv.y;
      w[j][c4 * 4 + 2] = wv.z;
      w[j][c4 * 4 + 3] = wv.w;
    }
    bias[j] = b_comb[e0 + j];
  }
  __syncthreads();

  // ---- Phase C: GEMM (broadcast ds_read_b128, nontemporal streamed out) ----
  const float* srow = sbuf + half * (CHUNK / 2) * C;
  float* orow = out + ((size_t)b * T + t0 + half * (CHUNK / 2)) * D + e0;

#pragma unroll 2
  for (int t = 0; t < CHUNK / 2; ++t) {
    float a[4], a2[4];
#pragma unroll
    for (int j = 0; j < 4; ++j) { a[j] = bias[j]; a2[j] = 0.f; }
    const float4* sr4 = (const float4*)(srow + t * C);
#pragma unroll
    for (int c4 = 0; c4 < C / 4; ++c4) {
      float4 sv = sr4[c4];  // broadcast ds_read_b128
      int cc = c4 * 4;
#pragma unroll
      for (int j = 0; j < 4; ++j) {
        a[j]  += sv.x * w[j][cc + 0];
        a2[j] += sv.y * w[j][cc + 1];
        a[j]  += sv.z * w[j][cc + 2];
        a2[j] += sv.w * w[j][cc + 3];
      }
    }
    floatx4 o;
    o.x = a[0] + a2[0];
    o.y = a[1] + a2[1];
    o.z = a[2] + a2[2];
    o.w = a[3] + a2[3];
    __builtin_nontemporal_store(o, (floatx4*)(orow + (size_t)t * D));
  }
}

// ---------------------------------------------------------------------------
extern "C" void kernel_launch(void* const* d_in, const int* in_sizes, int n_in,
                              void* d_out, int out_size, void* d_ws, size_t ws_size,
                              hipStream_t stream) {
  const float* x     = (const float*)d_in[0];  // [B,C,T]
  const float* W_ve  = (const float*)d_in[1];  // [D,C]
  const float* b_ve  = (const float*)d_in[2];  // [D]
  const float* W_lin = (const float*)d_in[3];  // [D,D]
  const float* b_lin = (const float*)d_in[4];  // [D]
  float* out = (float*)d_out;                  // [B,T,D]

  // workspace: W_comb [D*C], b_comb [D]
  float* W_comb = (float*)d_ws;
  float* b_comb = W_comb + (size_t)D * C;

  combine_weights<<<D, 256, 0, stream>>>(W_ve, b_ve, W_lin, b_lin, W_comb, b_comb);
  fused_main<<<dim3(T / CHUNK, B), 256, 0, stream>>>(x, W_comb, b_comb, out);
}